// Round 2
// 326.619 us; speedup vs baseline: 1.0091x; 1.0091x over previous
//
#include <hip/hip_runtime.h>

#define D 128
#define OUTD 64
#define LAYERS 3
#define MAXBK 512   // max buckets (node>>7); N=50000 -> 391

typedef __attribute__((ext_vector_type(8))) short short8;
typedef __attribute__((ext_vector_type(4))) float float4v;
typedef __attribute__((ext_vector_type(2))) float floatx2;
typedef unsigned int uint32;

static inline int ceil_div(int a, int b) { return (a + b - 1) / b; }

__device__ __forceinline__ unsigned short f2bf(float f) {
    unsigned int u = __float_as_uint(f);
    unsigned int r = u + 0x7FFFu + ((u >> 16) & 1u);
    return (unsigned short)(r >> 16);
}

// feature permutation: storage element position of logical feature f.
__device__ __forceinline__ int fperm(int f) { return (f & 15) * 8 + (f >> 4); }

// ---------------- prep: combined bucket hist + all converts ----------------

#define BH_BLOCKS  64
#define CVX_BLOCKS 1044

__global__ __launch_bounds__(256)
void prep(const int* __restrict__ src, const int* __restrict__ dst, int E, int N, int NBK,
          int* bc,
          const float* __restrict__ x, short* __restrict__ xb,
          const float* __restrict__ Wself, const float* __restrict__ Wstd,
          const float* __restrict__ Wdts, const float* __restrict__ Wlin,
          const float* __restrict__ bself, const float* __restrict__ bstd,
          const float* __restrict__ bdts, const float* __restrict__ alpha_p,
          short* __restrict__ wt, short* __restrict__ wlt, float* __restrict__ bcombp) {
    __shared__ int bh[MAXBK];
    int b = blockIdx.x;
    if (b < BH_BLOCKS) {
        // combined per-bucket record counts (in + out records land in dest/src node buckets)
        for (int i = threadIdx.x; i < MAXBK; i += 256) bh[i] = 0;
        __syncthreads();
        int per = (E + BH_BLOCKS - 1) / BH_BLOCKS;
        int lo = b * per, hi = min(E, lo + per);
        for (int e = lo + threadIdx.x; e < hi; e += 256) {
            int s = src[e], d = dst[e];
            atomicAdd(&bh[d >> 7], 1);
            atomicAdd(&bh[s >> 7], 1);
        }
        __syncthreads();
        for (int i = threadIdx.x; i < NBK; i += 256) {
            if (bh[i]) atomicAdd(&bc[i], bh[i]);
        }
    } else if (b < BH_BLOCKS + CVX_BLOCKS) {
        int total = N * 16;
        for (int i = (b - BH_BLOCKS) * 256 + threadIdx.x; i < total; i += CVX_BLOCKS * 256) {
            int n = i >> 4, q = i & 15;
            const float* xr = x + (size_t)n * D + q;
            short8 s;
            #pragma unroll
            for (int fh = 0; fh < 8; fh++) s[fh] = (short)f2bf(xr[fh * 16]);
            *(short8*)(xb + (size_t)n * D + q * 8) = s;
        }
    } else {
        int cb = b - BH_BLOCKS - CVX_BLOCKS;   // 0..10
        if (cb < 9) {
            int l = cb / 3, m = cb % 3;
            const float* W = (m == 0 ? Wself : (m == 1 ? Wstd : Wdts)) + (size_t)l * D * D;
            short* o = wt + (size_t)cb * D * D;
            for (int idx = threadIdx.x; idx < D * D; idx += 256) {
                int k = idx >> 7, n = idx & 127;
                o[n * D + fperm(k)] = (short)f2bf(W[idx]);
            }
        } else if (cb == 9) {
            for (int idx = threadIdx.x; idx < D * OUTD; idx += 256) {
                int k = idx >> 6, n = idx & 63;
                wlt[n * D + fperm(k)] = (short)f2bf(Wlin[idx]);
            }
        } else {
            float a = alpha_p[0];
            for (int i = threadIdx.x; i < LAYERS * D; i += 256) {
                int l = i >> 7, j = i & 127;
                bcombp[l * D + fperm(j)] = bself[i] + (1.0f - a) * bstd[i] + a * bdts[i];
            }
        }
    }
}

// ---------------- scan over NBK buckets (NBK <= 512 fits one 1024-block pass) ----------------

__global__ __launch_bounds__(1024)
void scan1(const int* __restrict__ bc, int* __restrict__ off, int* __restrict__ bcur, int n) {
    __shared__ int wsum[16];
    __shared__ int total;
    int tid = threadIdx.x, lane = tid & 63, w = tid >> 6;
    int v = (tid < n) ? bc[tid] : 0;
    int x = v;
    #pragma unroll
    for (int o = 1; o < 64; o <<= 1) {
        int y = __shfl_up(x, o, 64);
        if (lane >= o) x += y;
    }
    if (lane == 63) wsum[w] = x;
    __syncthreads();
    if (w == 0 && lane < 16) {
        int s = wsum[lane];
        #pragma unroll
        for (int o = 1; o < 16; o <<= 1) {
            int y = __shfl_up(s, o, 16);
            if (lane >= o) s += y;
        }
        wsum[lane] = s;
        if (lane == 15) total = s;
    }
    __syncthreads();
    int wpre = w ? wsum[w - 1] : 0;
    if (tid < n) {
        int e = wpre + x - v;
        off[tid] = e;
        bcur[tid] = e;
    }
    if (tid == 0) off[n] = total;
}

// ---------------- slim GEMM body: A direct from global, B staged in caller's LDS ----------------

__device__ __forceinline__ void gemm3_body(int mtile, int z, const short* __restrict__ Abf,
                                           int M, const short* __restrict__ wt3,
                                           short* __restrict__ t1b,
                                           uint32* __restrict__ t2q, uint32* __restrict__ t3q,
                                           short* Bs) {   // Bs: 128*136 shorts
    int tid = threadIdx.x;
    int m0 = mtile * 128;
    const short* Bt = wt3 + (size_t)z * D * D;

    #pragma unroll
    for (int i = 0; i < 8; i++) {
        int v = tid + i * 256;
        int row = v >> 4, c8 = v & 15;
        *(short8*)&Bs[row * 136 + c8 * 8] = *(const short8*)(Bt + (size_t)row * D + c8 * 8);
    }
    __syncthreads();

    int wave = tid >> 6, lane = tid & 63;
    int quad = lane >> 4, r16 = lane & 15;
    int mrow = wave * 32;
    int gr0 = m0 + mrow + r16;
    int gr1 = gr0 + 16;

    float4v acc[2][8];
    #pragma unroll
    for (int a = 0; a < 2; a++)
        #pragma unroll
        for (int b = 0; b < 8; b++)
            acc[a][b] = (float4v){0.f, 0.f, 0.f, 0.f};

    #pragma unroll
    for (int kc = 0; kc < 4; kc++) {
        short8 a0 = {0, 0, 0, 0, 0, 0, 0, 0};
        short8 a1 = {0, 0, 0, 0, 0, 0, 0, 0};
        if (gr0 < M) a0 = *(const short8*)(Abf + (size_t)gr0 * D + kc * 32 + quad * 8);
        if (gr1 < M) a1 = *(const short8*)(Abf + (size_t)gr1 * D + kc * 32 + quad * 8);
        #pragma unroll
        for (int nt = 0; nt < 8; nt++) {
            short8 b = *(const short8*)&Bs[(nt * 16 + r16) * 136 + kc * 32 + quad * 8];
            acc[0][nt] = __builtin_amdgcn_mfma_f32_16x16x32_bf16(a0, b, acc[0][nt], 0, 0, 0);
            acc[1][nt] = __builtin_amdgcn_mfma_f32_16x16x32_bf16(a1, b, acc[1][nt], 0, 0, 0);
        }
    }

    #pragma unroll
    for (int rt = 0; rt < 2; rt++)
        #pragma unroll
        for (int reg = 0; reg < 4; reg++) {
            int row = m0 + mrow + rt * 16 + quad * 4 + reg;
            if (row >= M) continue;
            if (z == 0) {
                short8 s8;
                #pragma unroll
                for (int nt = 0; nt < 8; nt++) s8[nt] = (short)f2bf(acc[rt][nt][reg]);
                *(short8*)(t1b + (size_t)row * D + r16 * 8) = s8;
            } else {
                uint32 u0 = __builtin_amdgcn_cvt_pk_fp8_f32(acc[rt][0][reg], acc[rt][1][reg], 0, false);
                u0 = __builtin_amdgcn_cvt_pk_fp8_f32(acc[rt][2][reg], acc[rt][3][reg], u0, true);
                uint32 u1 = __builtin_amdgcn_cvt_pk_fp8_f32(acc[rt][4][reg], acc[rt][5][reg], 0, false);
                u1 = __builtin_amdgcn_cvt_pk_fp8_f32(acc[rt][6][reg], acc[rt][7][reg], u1, true);
                uint32* dq = ((z == 1) ? t2q : t3q) + (size_t)row * 32 + r16 * 2;
                *(uint2*)dq = make_uint2(u0, u1);
            }
        }
}

// ---------------- build: binned edge append (combined records) + fused layer-0 GEMM ----------------
// record = payload << 7 | (node & 127); payload = src (in-edge, gather t2q) or
// dst + N (out-edge, gather t3q). t2q/t3q contiguous -> payload IS the row index.

#define AP_BLOCKS 128

__global__ __launch_bounds__(256)
void build_gemm0(const int* __restrict__ src, const int* __restrict__ dst, int E, int N,
                 int NBK, int* bcur, uint32* __restrict__ ebuf,
                 const short* __restrict__ xb, const short* __restrict__ wt,
                 short* __restrict__ t1b, uint32* __restrict__ t2q, uint32* __restrict__ t3q) {
    __shared__ __align__(16) short smem[128 * 136];
    int b = blockIdx.x;
    if (b < AP_BLOCKS) {
        int* h = (int*)smem;          // MAXBK ints
        for (int i = threadIdx.x; i < MAXBK; i += 256) h[i] = 0;
        __syncthreads();
        int per = (E + AP_BLOCKS - 1) / AP_BLOCKS;
        int lo = b * per, hi = min(E, lo + per);
        for (int e = lo + threadIdx.x; e < hi; e += 256) {
            int s = src[e], d = dst[e];
            atomicAdd(&h[d >> 7], 1);
            atomicAdd(&h[s >> 7], 1);
        }
        __syncthreads();
        for (int i = threadIdx.x; i < NBK; i += 256) {
            int c = h[i];
            h[i] = c ? atomicAdd(&bcur[i], c) : 0;
        }
        __syncthreads();
        for (int e = lo + threadIdx.x; e < hi; e += 256) {
            int s = src[e], d = dst[e];
            int p = atomicAdd(&h[d >> 7], 1);
            ebuf[p] = ((uint32)s << 7) | (uint32)(d & 127);
            int q = atomicAdd(&h[s >> 7], 1);
            ebuf[q] = ((uint32)(d + N) << 7) | (uint32)(s & 127);
        }
    } else {
        int g = b - AP_BLOCKS;
        gemm3_body(g / 3, g % 3, xb, N, wt, t1b, t2q, t3q, smem);
    }
}

// ---------------- bucket_count_fill: per-(node,tag) count + rowx write + col fill ----------------
// rowx[2n] = in-segment start, rowx[2n+1] = out-segment start, rowx[2n+2] = end.
// In-records (payload < N) sorted before out-records per node.

__global__ __launch_bounds__(256)
void bucket_count_fill(const uint32* __restrict__ ebuf, const int* __restrict__ off,
                       int* __restrict__ rowx, int* __restrict__ col, int N, int NBK) {
    __shared__ int cnt[256];
    __shared__ int wsum4[4];
    __shared__ int lcur[256];
    int k = blockIdx.x;
    int nb = k << 7;
    int tid = threadIdx.x;
    cnt[tid] = 0;
    __syncthreads();
    int lo = off[k], hi = off[k + 1];
    for (int r = lo + tid; r < hi; r += 256) {
        uint32 rec = ebuf[r];
        int t = ((rec >> 7) >= (uint32)N) ? 1 : 0;
        atomicAdd(&cnt[((rec & 127u) << 1) | t], 1);
    }
    __syncthreads();
    int lane = tid & 63, w = tid >> 6;
    int v = cnt[tid];
    int x = v;
    #pragma unroll
    for (int o = 1; o < 64; o <<= 1) {
        int y = __shfl_up(x, o, 64);
        if (lane >= o) x += y;
    }
    if (lane == 63) wsum4[w] = x;
    __syncthreads();
    if (tid == 0) {
        int s = 0;
        #pragma unroll
        for (int i = 0; i < 4; i++) { int t = wsum4[i]; wsum4[i] = s; s += t; }
    }
    __syncthreads();
    int excl = lo + wsum4[w] + x - v;
    int node = nb + (tid >> 1);
    if (node < N) rowx[(node << 1) | (tid & 1)] = excl;
    lcur[tid] = excl;
    if (k == NBK - 1 && tid == 0) rowx[2 * N] = hi;
    __syncthreads();
    for (int r = lo + tid; r < hi; r += 256) {
        uint32 rec = ebuf[r];
        int t = ((rec >> 7) >= (uint32)N) ? 1 : 0;
        int slot = atomicAdd(&lcur[((rec & 127u) << 1) | t], 1);
        col[slot] = (int)(rec >> 7);
    }
}

__global__ __launch_bounds__(256)
void gemm3_k(const short* __restrict__ hin, int M, const short* __restrict__ wt3,
             short* __restrict__ t1b, uint32* __restrict__ t2q, uint32* __restrict__ t3q) {
    __shared__ __align__(16) short smem[128 * 136];
    gemm3_body(blockIdx.x, blockIdx.z, hin, M, wt3, t1b, t2q, t3q, smem);
}

// ---------------- Final GEMM (MFMA, slim) ----------------

__global__ __launch_bounds__(256)
void gemm_out_mfma(const short* __restrict__ jkb, int M, const short* __restrict__ wlt,
                   const float* __restrict__ blin, float* __restrict__ Cout) {
    __shared__ __align__(16) short Bs[64][136];
    int tid = threadIdx.x;
    int m0 = blockIdx.x * 128;

    #pragma unroll
    for (int i = 0; i < 4; i++) {
        int v = tid + i * 256;
        int row = v >> 4, c8 = v & 15;
        *(short8*)&Bs[row][c8 * 8] = *(const short8*)(wlt + (size_t)row * D + c8 * 8);
    }
    __syncthreads();

    int wave = tid >> 6, lane = tid & 63;
    int quad = lane >> 4, r16 = lane & 15;
    int mrow = wave * 32;
    int gr0 = m0 + mrow + r16;
    int gr1 = gr0 + 16;

    float4v acc[2][4];
    #pragma unroll
    for (int a = 0; a < 2; a++)
        #pragma unroll
        for (int b = 0; b < 4; b++)
            acc[a][b] = (float4v){0.f, 0.f, 0.f, 0.f};

    #pragma unroll
    for (int kc = 0; kc < 4; kc++) {
        short8 a0 = {0, 0, 0, 0, 0, 0, 0, 0};
        short8 a1 = {0, 0, 0, 0, 0, 0, 0, 0};
        if (gr0 < M) a0 = *(const short8*)(jkb + (size_t)gr0 * D + kc * 32 + quad * 8);
        if (gr1 < M) a1 = *(const short8*)(jkb + (size_t)gr1 * D + kc * 32 + quad * 8);
        #pragma unroll
        for (int nt = 0; nt < 4; nt++) {
            short8 b = *(const short8*)&Bs[nt * 16 + r16][kc * 32 + quad * 8];
            acc[0][nt] = __builtin_amdgcn_mfma_f32_16x16x32_bf16(a0, b, acc[0][nt], 0, 0, 0);
            acc[1][nt] = __builtin_amdgcn_mfma_f32_16x16x32_bf16(a1, b, acc[1][nt], 0, 0, 0);
        }
    }

    #pragma unroll
    for (int rt = 0; rt < 2; rt++)
        #pragma unroll
        for (int nt = 0; nt < 4; nt++)
            #pragma unroll
            for (int reg = 0; reg < 4; reg++) {
                int row = m0 + mrow + rt * 16 + quad * 4 + reg;
                int col = nt * 16 + r16;
                if (row < M) Cout[(size_t)row * OUTD + col] = acc[rt][nt][reg] + blin[col];
            }
}

// ---------------- Fused aggregation: segment-split, shfl-free inner loop ----------------
// One wave per node. Records per node stored [in-segment | out-segment] (contiguous).
// Per 8 edges: 2 direct col loads (16 lanes share an address -> L1 broadcast),
// 2 cndmask (tail lanes gather the padded all-zero fp8 row at index 2N),
// 2 uint2 gathers, 8 cvt_pk_f32_fp8, 8 packed adds. No cross-lane ops, no
// per-edge weights: in/out sums are accumulated raw and scaled by the
// wave-uniform win/wout before the cross-lane reduction (scaling commutes
// with the lane-sum).

__device__ __forceinline__ void seg_accum(const uint2* __restrict__ tq2,
                                          const int* __restrict__ col,
                                          int lo, int hi, int rgrp, int c, int ZR,
                                          floatx2& A0, floatx2& A1,
                                          floatx2& A2, floatx2& A3) {
    for (int p = lo; p < hi; p += 8) {
        int e0 = p + rgrp;
        int e1 = e0 + 4;
        int i0 = col[e0];          // col is padded; loads past hi are safe
        int i1 = col[e1];
        int rec0 = (e0 < hi) ? i0 : ZR;
        int rec1 = (e1 < hi) ? i1 : ZR;
        uint2 v0 = tq2[rec0 * 16 + c];
        uint2 v1 = tq2[rec1 * 16 + c];
        A0 += __builtin_amdgcn_cvt_pk_f32_fp8(v0.x, false);
        A1 += __builtin_amdgcn_cvt_pk_f32_fp8(v0.x, true);
        A2 += __builtin_amdgcn_cvt_pk_f32_fp8(v0.y, false);
        A3 += __builtin_amdgcn_cvt_pk_f32_fp8(v0.y, true);
        A0 += __builtin_amdgcn_cvt_pk_f32_fp8(v1.x, false);
        A1 += __builtin_amdgcn_cvt_pk_f32_fp8(v1.x, true);
        A2 += __builtin_amdgcn_cvt_pk_f32_fp8(v1.y, false);
        A3 += __builtin_amdgcn_cvt_pk_f32_fp8(v1.y, true);
    }
}

__global__ __launch_bounds__(256)
void agg_epilogue(const short* __restrict__ t1b,
                  const uint32* __restrict__ tq,       // 2N+1 fp8 rows (t2q|t3q|zero)
                  const float* __restrict__ bcombp,
                  const int* __restrict__ rowx, const int* __restrict__ col,
                  const float* __restrict__ alpha_p,
                  short* __restrict__ h_out, short* __restrict__ jkb,
                  int first, int N) {
    int wv = threadIdx.x >> 6;
    int lane = threadIdx.x & 63;
    int n = blockIdx.x * 4 + wv;
    if (n >= N) return;
    float a = alpha_p[0];
    int2 r01 = *(const int2*)(rowx + 2 * n);
    int r0 = r01.x, r1 = r01.y, r2 = rowx[2 * n + 2];
    float win = (1.0f - a) / (float)max(r1 - r0, 1);
    float wout = a / (float)max(r2 - r1, 1);
    int rgrp = lane >> 4;
    int c = lane & 15;
    int ZR = 2 * N;
    const uint2* tq2 = (const uint2*)tq;

    floatx2 A0 = {0.f, 0.f}, A1 = {0.f, 0.f}, A2 = {0.f, 0.f}, A3 = {0.f, 0.f};
    floatx2 B0 = {0.f, 0.f}, B1 = {0.f, 0.f}, B2 = {0.f, 0.f}, B3 = {0.f, 0.f};

    seg_accum(tq2, col, r0, r1, rgrp, c, ZR, A0, A1, A2, A3);   // in-records
    seg_accum(tq2, col, r1, r2, rgrp, c, ZR, B0, B1, B2, B3);   // out-records

    // fold in wave-uniform weights, then reduce across the 4 row-groups
    floatx2 wi = {win, win}, wo = {wout, wout};
    A0 = A0 * wi + B0 * wo;
    A1 = A1 * wi + B1 * wo;
    A2 = A2 * wi + B2 * wo;
    A3 = A3 * wi + B3 * wo;

    #define RED(X) \
        X.x += __shfl_xor(X.x, 16, 64); X.y += __shfl_xor(X.y, 16, 64); \
        X.x += __shfl_xor(X.x, 32, 64); X.y += __shfl_xor(X.y, 32, 64);
    RED(A0) RED(A1) RED(A2) RED(A3)
    #undef RED

    if (lane < 16) {
        // lane c owns permuted elements c*8 .. c*8+7
        uint4 tv = *(const uint4*)(t1b + (size_t)n * D + c * 8);
        float4 b0 = *(const float4*)(bcombp + c * 8);
        float4 b1 = *(const float4*)(bcombp + c * 8 + 4);
        float h0 = fmaxf(__uint_as_float(tv.x << 16)          + b0.x + A0.x, 0.f);
        float h1 = fmaxf(__uint_as_float(tv.x & 0xFFFF0000u)  + b0.y + A0.y, 0.f);
        float h2 = fmaxf(__uint_as_float(tv.y << 16)          + b0.z + A1.x, 0.f);
        float h3 = fmaxf(__uint_as_float(tv.y & 0xFFFF0000u)  + b0.w + A1.y, 0.f);
        float h4 = fmaxf(__uint_as_float(tv.z << 16)          + b1.x + A2.x, 0.f);
        float h5 = fmaxf(__uint_as_float(tv.z & 0xFFFF0000u)  + b1.y + A2.y, 0.f);
        float h6 = fmaxf(__uint_as_float(tv.w << 16)          + b1.z + A3.x, 0.f);
        float h7 = fmaxf(__uint_as_float(tv.w & 0xFFFF0000u)  + b1.w + A3.y, 0.f);
        uint32 p0 = (uint32)f2bf(h0) | ((uint32)f2bf(h1) << 16);
        uint32 p1 = (uint32)f2bf(h2) | ((uint32)f2bf(h3) << 16);
        uint32 p2 = (uint32)f2bf(h4) | ((uint32)f2bf(h5) << 16);
        uint32 p3 = (uint32)f2bf(h6) | ((uint32)f2bf(h7) << 16);
        uint4 pk = make_uint4(p0, p1, p2, p3);
        if (h_out) *(uint4*)(h_out + (size_t)n * D + c * 8) = pk;
        uint4* jp = (uint4*)(jkb + (size_t)n * D + c * 8);
        if (first) {
            *jp = pk;
        } else {
            uint4 old = *jp;
            // relu'd bf16 >= 0 -> monotone as u16; per-half max
            uint32 q0 = max(old.x & 0xFFFFu, pk.x & 0xFFFFu) | max(old.x & 0xFFFF0000u, pk.x & 0xFFFF0000u);
            uint32 q1 = max(old.y & 0xFFFFu, pk.y & 0xFFFFu) | max(old.y & 0xFFFF0000u, pk.y & 0xFFFF0000u);
            uint32 q2 = max(old.z & 0xFFFFu, pk.z & 0xFFFFu) | max(old.z & 0xFFFF0000u, pk.z & 0xFFFF0000u);
            uint32 q3 = max(old.w & 0xFFFFu, pk.w & 0xFFFFu) | max(old.w & 0xFFFF0000u, pk.w & 0xFFFF0000u);
            *jp = make_uint4(q0, q1, q2, q3);
        }
    }
}

// ---------------- launch ----------------

extern "C" void kernel_launch(void* const* d_in, const int* in_sizes, int n_in,
                              void* d_out, int out_size, void* d_ws, size_t ws_size,
                              hipStream_t stream) {
    const float* x     = (const float*)d_in[0];
    const int*   ei    = (const int*)d_in[1];
    const float* Wself = (const float*)d_in[2];
    const float* bself = (const float*)d_in[3];
    const float* Wstd  = (const float*)d_in[4];
    const float* bstd  = (const float*)d_in[5];
    const float* Wdts  = (const float*)d_in[6];
    const float* bdts  = (const float*)d_in[7];
    const float* Wlin  = (const float*)d_in[8];
    const float* blin  = (const float*)d_in[9];
    const float* alpha = (const float*)d_in[10];

    int N = in_sizes[0] / D;   // 50000
    int E = in_sizes[1] / 2;   // 800000
    int NBK = ceil_div(N, 128);

    char* p = (char*)d_ws;
    auto alloc = [&](size_t bytes) {
        char* q = p;
        p += (bytes + 255) & ~(size_t)255;
        return q;
    };
    int* bc    = (int*)alloc((size_t)MAXBK * 4);       // zeroed
    char* zero_end = p;
    int* off   = (int*)alloc((size_t)(MAXBK + 1) * 4);
    int* bcur  = (int*)alloc((size_t)(MAXBK + 1) * 4);
    int* rowx  = (int*)alloc((size_t)(2 * N + 2) * 4);
    uint32* ebuf = (uint32*)alloc((size_t)2 * E * 4);
    int* col   = (int*)alloc((size_t)(2 * E + 64) * 4);
    short* xb    = (short*)alloc((size_t)N * D * 2);
    short* hb    = (short*)alloc((size_t)N * D * 2);
    short* wt    = (short*)alloc((size_t)9 * D * D * 2);
    short* wlt   = (short*)alloc((size_t)D * OUTD * 2);
    float* bcombp = (float*)alloc((size_t)LAYERS * D * 4);
    short* t1b   = (short*)alloc((size_t)N * D * 2);
    uint32* tq   = (uint32*)alloc(((size_t)2 * N + 1) * 32 * 4);  // fp8 rows: [t2q | t3q | zero]
    short* jkb   = (short*)alloc((size_t)N * D * 2);

    uint32* t2q = tq;
    uint32* t3q = tq + (size_t)N * 32;

    const int* srcp = ei;
    const int* dstp = ei + E;

    hipMemsetAsync(bc, 0, (size_t)(zero_end - (char*)bc), stream);
    hipMemsetAsync(tq + (size_t)2 * N * 32, 0, 128, stream);   // zero pad row (index 2N)

    prep<<<BH_BLOCKS + CVX_BLOCKS + 11, 256, 0, stream>>>(
        srcp, dstp, E, N, NBK, bc, x, xb,
        Wself, Wstd, Wdts, Wlin, bself, bstd, bdts, alpha, wt, wlt, bcombp);
    scan1<<<1, 1024, 0, stream>>>(bc, off, bcur, NBK);

    int gm = ceil_div(N, 128);
    build_gemm0<<<AP_BLOCKS + 3 * gm, 256, 0, stream>>>(
        srcp, dstp, E, N, NBK, bcur, ebuf, xb, wt, t1b, t2q, t3q);
    bucket_count_fill<<<NBK, 256, 0, stream>>>(ebuf, off, rowx, col, N, NBK);

    for (int l = 0; l < LAYERS; l++) {
        agg_epilogue<<<ceil_div(N, 4), 256, 0, stream>>>(
            t1b, tq, bcombp + (size_t)l * D, rowx, col, alpha,
            (l == LAYERS - 1) ? nullptr : hb, jkb, (l == 0) ? 1 : 0, N);
        if (l < LAYERS - 1)
            gemm3_k<<<dim3(gm, 1, 3), 256, 0, stream>>>(hb, N, wt + (size_t)(l + 1) * 3 * D * D,
                                                        t1b, t2q, t3q);
    }
    gemm_out_mfma<<<gm, 256, 0, stream>>>(jkb, N, wlt, blin, (float*)d_out);
}